// Round 9
// baseline (266.296 us; speedup 1.0000x reference)
//
#include <hip/hip_runtime.h>

// Problem constants
#define Bv 2
#define Hv 8
#define Lv 512
#define DKv 16
#define DMv 128          // H*DK
#define NKv 10
#define KSv 513

typedef __attribute__((ext_vector_type(8))) short short8;
typedef __attribute__((ext_vector_type(4))) float f32x4;

// chunk tables: nc_g = ceil((2^g+1)/16); chunks aligned to the END of the kernel
__device__ __constant__ int d_nc[10]     = {1,1,1,1,2,3,5,9,17,33};
__device__ __constant__ int d_cumnc[10]  = {0,1,2,3,4,6,9,14,23,40};
// conv work groups: <=3 consecutive chunks of one g; groups 0..5 own their
// whole g (plain store), 6..27 are K-splits of g>=6 (atomicAdd)
__device__ __constant__ signed char d_gg[28]   = {0,1,2,3,4,5,6,6,7,7,7,8,8,8,8,8,8,9,9,9,9,9,9,9,9,9,9,9};
__device__ __constant__ signed char d_gcl0[28] = {0,0,0,0,0,0,0,3,0,3,6,0,3,6,9,12,15,0,3,6,9,12,15,18,21,24,27,30};
__device__ __constant__ signed char d_gnch[28] = {1,1,1,1,2,3,3,2,3,3,3,3,3,3,3,3,2,3,3,3,3,3,3,3,3,3,3,3};

// ws layout (bytes):
//   Y  : f32 [2 p][10 g][2 b][128 o][512 t]            = 10,485,760 B
//   xr : bf16 [2 p][2 b][512 t][128 i]                 =    524,288 B
//   Wb : bf16 [g][Tlocal][ A-frag layout ]             = 38,273,024 B
//        plane off(o,i) = ((o>>4)*4 + (i>>5))*512 + (o&15)*32 + (i&31)
#define Y_BYTES   (10485760)
#define XR_OFF    (Y_BYTES)
#define WB_OFF    (Y_BYTES + 524288)

__device__ inline unsigned short f2bf(float f) {
    unsigned u = __float_as_uint(f);
    unsigned r = (u + 0x7FFFu + ((u >> 16) & 1u)) >> 16;
    return (unsigned short)r;
}

// ---------------------------------------------------------------------------
// prep: fused  (a) zero Y planes g6..g9 (both p)  (b) attn_out := 1.0
//              (c) repack_x  xr[p][b][t][i] = bf16(flat Q/K)
// item map (f4-ish units): [0,131072) YzeroA, [131072,262144) YzeroB,
//                          [262144,1310720) ones, [1310720,1376256) repack_x
__global__ void prep(const float* __restrict__ Q, const float* __restrict__ K,
                     unsigned short* __restrict__ xr,
                     float4* __restrict__ Y4, float4* __restrict__ out4) {
    int stride = gridDim.x * 256;
    for (int i = blockIdx.x * 256 + threadIdx.x; i < 1376256; i += stride) {
        if (i < 131072) {
            Y4[196608 + i] = make_float4(0.f, 0.f, 0.f, 0.f);          // p0 g6..9
        } else if (i < 262144) {
            Y4[524288 + (i - 131072)] = make_float4(0.f, 0.f, 0.f, 0.f); // p1 g6..9
        } else if (i < 1310720) {
            out4[32768 + (i - 262144)] = make_float4(1.f, 1.f, 1.f, 1.f);
        } else {
            int idx = i - 1310720;               // 65536 items of 4 floats
            int flat = idx * 4;
            int p = flat >> 17;
            int off = flat & 131071;
            const float* src = p ? K : Q;
            float4 v = *(const float4*)(src + off);
            ushort4 o;
            o.x = f2bf(v.x); o.y = f2bf(v.y); o.z = f2bf(v.z); o.w = f2bf(v.w);
            *(ushort4*)(((unsigned short*)xr) + flat) = o;
        }
    }
}

// ---------------------------------------------------------------------------
// Wb plane layout: off(o,i) = ((o>>4)*4 + (i>>5))*512 + (o&15)*32 + (i&31)
// One block per (chunk cid, o). Reads W[g][o*128+i][tapcol], writes 16 taps.
__global__ __launch_bounds__(256) void repack_w(const float* __restrict__ W,
                                                unsigned short* __restrict__ wb) {
    int bid = blockIdx.x;
    int cid = bid >> 7;
    int o = bid & 127;
    int g, rem = cid;
#pragma unroll
    for (g = 0; g < 10; ++g) { int nc = d_nc[g]; if (rem < nc) break; rem -= nc; }
    int cl = rem;
    int w_g = d_nc[g] * 16;
    int ccol = w_g - 16 * (cl + 1);
    int wcolbase = 513 - w_g + ccol;      // absolute W col of this chunk's tap 0

    __shared__ float tile[128][17];       // [i][tap]
    const float* wsrc = W + (size_t)g * 16384 * 513 + (size_t)o * 128 * 513;
    int tid = threadIdx.x;
    int rr = tid >> 4, cc = tid & 15;
    int col = wcolbase + cc;
    for (int r = rr; r < 128; r += 16) {          // r = i
        float v = 0.f;
        if (col >= 0) v = wsrc[(size_t)r * 513 + col];
        tile[r][cc] = v;
    }
    __syncthreads();

    unsigned short* wdst = wb + (size_t)262144 * d_cumnc[g];
    int c2 = tid >> 4;          // tap 0..15
    int s  = tid & 15;          // ib(2) | qv(2)
    int ib = s >> 2, qv = s & 3;
    int i0 = ib * 32 + qv * 8;
    unsigned short pack[8];
#pragma unroll
    for (int e = 0; e < 8; ++e) pack[e] = f2bf(tile[i0 + e][c2]);
    size_t off = (size_t)(ccol + c2) * 16384 +
                 (((o >> 4) * 4 + ib) * 512 + (o & 15) * 32 + qv * 8);
    *(short8*)(wdst + off) = *(short8*)pack;      // 16B contiguous per thread
}

// ---------------------------------------------------------------------------
// conv v6: block = (group, yy). Tile M=128 o x N=256 t, 4 waves (2wm x 2wn).
// Per chunk in group: stage xs window (272 rows), 16-tap loop with A-frags
// streamed L2->regs (coalesced 1KB wave-loads). Groups 0..5 plain-store,
// others atomicAdd. Grid 256: j -> r=j&7 (XCD), yy=(j>>3)&7, grp=(j>>6)*8+r
// -> a group's 8 yy-siblings share one XCD (A-planes L2-resident).
__global__ __launch_bounds__(256, 2) void conv_mfma(const unsigned short* __restrict__ xr,
                                                    const unsigned short* __restrict__ wb,
                                                    float* __restrict__ Y) {
    int j = blockIdx.x;
    int r = j & 7, yy = (j >> 3) & 7, gq = j >> 6;
    int grp = gq * 8 + r;
    if (grp >= 28) return;
    int g = d_gg[grp], cl0 = d_gcl0[grp], nch = d_gnch[grp];
    int w_g = d_nc[g] * 16;

    int p = yy >> 2, b = (yy >> 1) & 1, tt = yy & 1;
    int t0 = tt * 256;
    int pb = yy >> 1;

    // xs: element (u,i) at u*128 + (((i>>3)+u)&15)*8 + (i&7); 272 rows
    __shared__ unsigned short xs[272 * 128];

    int tid = threadIdx.x;
    int lane = tid & 63, wv = tid >> 6;     // 4 waves: 2 wm x 2 wn
    int wm = wv >> 1, wn = wv & 1;
    int l15 = lane & 15, q = lane >> 4;

    const unsigned short* wgp_g = wb + (size_t)262144 * d_cumnc[g];
    const unsigned short* xp = xr + (size_t)pb * 65536;
    int abase = l15 * 32 + q * 8;

    f32x4 acc[4][8];
#pragma unroll
    for (int mt = 0; mt < 4; ++mt)
#pragma unroll
        for (int nt = 0; nt < 8; ++nt) acc[mt][nt] = (f32x4)0.f;

    int did = 0;
    for (int cc = 0; cc < nch; ++cc) {
        int cl = cl0 + cc;
        int ccol = w_g - 16 * (cl + 1);
        int xbase = t0 + 1 - 16 * (cl + 1);    // x index of xs row 0
        if (xbase < -270) continue;            // window entirely before t=0
        did = 1;

        __syncthreads();                       // prev chunk readers done
        for (int e = tid; e < 272 * 16; e += 256) {
            int u = e >> 4, ic = e & 15;
            int xi = xbase + u;
            short8 v = (short8)0;
            if (xi >= 0 && xi < 512) v = *(const short8*)(xp + (size_t)xi * 128 + ic * 8);
            *(short8*)(&xs[u * 128 + (((ic + u) & 15) << 3)]) = v;
        }
        __syncthreads();

        const unsigned short* wgp = wgp_g + (size_t)ccol * 16384;
        for (int jj = 0; jj < 16; ++jj) {
            const unsigned short* tp = wgp + (size_t)jj * 16384;
            int row0 = wn * 128 + l15 + jj;
#pragma unroll
            for (int ib = 0; ib < 4; ++ib) {
                short8 a[4], bq[8];
#pragma unroll
                for (int mt = 0; mt < 4; ++mt)
                    a[mt] = *(const short8*)(tp + ((wm * 4 + mt) * 4 + ib) * 512 + abase);
#pragma unroll
                for (int nt = 0; nt < 8; ++nt) {
                    int row = row0 + nt * 16;
                    bq[nt] = *(const short8*)(&xs[row * 128 + (((ib * 4 + q + row) & 15) << 3)]);
                }
#pragma unroll
                for (int mt = 0; mt < 4; ++mt)
#pragma unroll
                    for (int nt = 0; nt < 8; ++nt)
                        acc[mt][nt] = __builtin_amdgcn_mfma_f32_16x16x32_bf16(
                            a[mt], bq[nt], acc[mt][nt], 0, 0, 0);
            }
        }
    }

    int complete = (grp <= 5);
    if (!did && !complete) return;

    // epilogue into Y[p][g][b][o][t]
    float* yp = Y + (((size_t)p * NKv + g) * 2 + b) * 65536;
    int orow = wm * 64 + q * 4;
    int tcol = t0 + wn * 128 + l15;
    if (complete) {
#pragma unroll
        for (int mt = 0; mt < 4; ++mt)
#pragma unroll
            for (int nt = 0; nt < 8; ++nt)
#pragma unroll
                for (int rr = 0; rr < 4; ++rr)
                    yp[(size_t)(orow + mt * 16 + rr) * 512 + tcol + nt * 16] =
                        acc[mt][nt][rr];
    } else {
#pragma unroll
        for (int mt = 0; mt < 4; ++mt)
#pragma unroll
            for (int nt = 0; nt < 8; ++nt)
#pragma unroll
                for (int rr = 0; rr < 4; ++rr)
                    atomicAdd(&yp[(size_t)(orow + mt * 16 + rr) * 512 + tcol + nt * 16],
                              acc[mt][nt][rr]);
    }
}

// ---------------------------------------------------------------------------
// Masked-entry context: ctx_masked[q,d] = 0.1 * sum_{k>q} S[k,d],
// S[k,d] = sum_g (K_p + bias). WRITES out ctx region.
__global__ __launch_bounds__(512) void suffix_ctx(const float* __restrict__ Y,
                                                  const float* __restrict__ bconv,
                                                  float* __restrict__ out) {
    int bh = blockIdx.x;        // 16
    int b = bh >> 3, h = bh & 7;
    int tid = threadIdx.x;
    int d = tid & 15;
    int s = tid >> 4;           // stripe 0..31, k in [s*16, s*16+16)

    __shared__ float tot[32][17];
    float S[16];
#pragma unroll
    for (int jv = 0; jv < 16; ++jv) {
        int k = s * 16 + jv;
        int o = h * 16 + (k >> 5);
        int t = (k & 31) * 16 + d;
        float acc = 0.f;
#pragma unroll
        for (int g = 0; g < NKv; ++g)
            acc += Y[(((size_t)(NKv + g) * 2 + b) * 65536) + (size_t)o * 512 + t]
                 + bconv[g * 128 + o];
        S[jv] = acc;
    }
    float mytot = 0.f;
#pragma unroll
    for (int jv = 0; jv < 16; ++jv) mytot += S[jv];
    tot[s][d] = mytot;
    __syncthreads();
    float run = 0.f;
    for (int s2 = s + 1; s2 < 32; ++s2) run += tot[s2][d];
#pragma unroll
    for (int jv = 15; jv >= 0; --jv) {
        int qv = s * 16 + jv;
        out[(((size_t)b * 8 + h) * 512 + qv) * 16 + d] = 0.1f * run;
        run += S[jv];
    }
}

// ---------------------------------------------------------------------------
// phase 2: unmasked (k<=q) part, online softmax over g, 512 threads
// (32 q x 16 kl, 2 ki) -> 2 waves/SIMD.
__global__ __launch_bounds__(512) void attn_phase2(const float* __restrict__ Y,
                                                   const float* __restrict__ bconv,
                                                   float* __restrict__ out) {
    int blk = blockIdx.x;          // 256
    int half = blk & 1;
    int pr = blk >> 1;             // 128 pairs
    int bh = pr >> 3;
    int qp = pr & 7;
    int b = bh >> 3, h = bh & 7;

    int qtA = qp, qtB = 15 - qp;
    int u0 = half ? 8 : 0, u1 = half ? 17 : 8;

    __shared__ float Qs[2][NKv * 640];   // [X][g*640 + q*20 + d]
    __shared__ float Ks[NKv * 640];

    int tid = threadIdx.x;

#pragma unroll
    for (int X = 0; X < 2; ++X) {
        int o = h * 16 + (X ? qtB : qtA);
        for (int e = tid; e < NKv * 128; e += 512) {
            int g = e >> 7, c = e & 127;
            float4 v = *(const float4*)(Y + (((size_t)g * 2 + b) * 65536) +
                                        (size_t)o * 512 + c * 4);
            float bb = bconv[g * 128 + o];
            int qq2 = c >> 2, dd = c & 3;
            *(float4*)&Qs[X][g * 640 + qq2 * 20 + dd * 4] =
                make_float4(v.x + bb, v.y + bb, v.z + bb, v.w + bb);
        }
    }

    int q = (tid >> 4) & 31;
    int kl = tid & 15;
    float ctx[16];
#pragma unroll
    for (int d = 0; d < 16; ++d) ctx[d] = 0.f;
    int curX = (u0 <= qtA) ? 0 : 1;

    for (int u = u0; u < u1; ++u) {
        int X = (u <= qtA) ? 0 : 1;
        int qt = X ? qtB : qtA;
        int kt = X ? (u - qtA - 1) : u;

        if (X != curX) {
            int pqt = curX ? qtB : qtA;
#pragma unroll
            for (int d = 0; d < 16; ++d) {
                float v = ctx[d];
                v += __shfl_xor(v, 1);
                v += __shfl_xor(v, 2);
                v += __shfl_xor(v, 4);
                v += __shfl_xor(v, 8);
                if (kl == 0)
                    atomicAdd(&out[(((size_t)b * 8 + h) * 512 + pqt * 32 + q) * 16 + d], v);
                ctx[d] = 0.f;
            }
            curX = X;
        }

        __syncthreads();
        int o_k = h * 16 + kt;
        for (int e = tid; e < NKv * 128; e += 512) {
            int g = e >> 7, c = e & 127;
            float4 v = *(const float4*)(Y + (((size_t)(NKv + g) * 2 + b) * 65536) +
                                        (size_t)o_k * 512 + c * 4);
            float bb = bconv[g * 128 + o_k];
            int kk = c >> 2, dd = c & 3;
            *(float4*)&Ks[g * 640 + kk * 20 + dd * 4] =
                make_float4(v.x + bb, v.y + bb, v.z + bb, v.w + bb);
        }
        __syncthreads();

        int qg = qt * 32 + q;
        bool dg = (kt == qt);

        float m[2] = {-1e30f, -1e30f};
        float l[2] = {0.f, 0.f};
        float ca[2][16];
#pragma unroll
        for (int ki = 0; ki < 2; ++ki)
#pragma unroll
            for (int d = 0; d < 16; ++d) ca[ki][d] = 0.f;

        for (int g = 0; g < NKv; ++g) {
            const float* Qg = &Qs[X][g * 640 + q * 20];
            float4 qv0 = *(const float4*)(Qg);
            float4 qv1 = *(const float4*)(Qg + 4);
            float4 qv2 = *(const float4*)(Qg + 8);
            float4 qv3 = *(const float4*)(Qg + 12);
#pragma unroll
            for (int ki = 0; ki < 2; ++ki) {
                const float* Kg = &Ks[g * 640 + (ki * 16 + kl) * 20];
                float kv[16];
                *(float4*)&kv[0]  = *(const float4*)(Kg);
                *(float4*)&kv[4]  = *(const float4*)(Kg + 4);
                *(float4*)&kv[8]  = *(const float4*)(Kg + 8);
                *(float4*)&kv[12] = *(const float4*)(Kg + 12);
                float s = 0.f;
                s = fmaf(qv0.x, kv[0], s);  s = fmaf(qv0.y, kv[1], s);
                s = fmaf(qv0.z, kv[2], s);  s = fmaf(qv0.w, kv[3], s);
                s = fmaf(qv1.x, kv[4], s);  s = fmaf(qv1.y, kv[5], s);
                s = fmaf(qv1.z, kv[6], s);  s = fmaf(qv1.w, kv[7], s);
                s = fmaf(qv2.x, kv[8], s);  s = fmaf(qv2.y, kv[9], s);
                s = fmaf(qv2.z, kv[10], s); s = fmaf(qv2.w, kv[11], s);
                s = fmaf(qv3.x, kv[12], s); s = fmaf(qv3.y, kv[13], s);
                s = fmaf(qv3.z, kv[14], s); s = fmaf(qv3.w, kv[15], s);
                s *= 0.25f;
                float mn = fmaxf(m[ki], s);
                float sc = __expf(m[ki] - mn);
                float w  = __expf(s - mn);
                m[ki] = mn;
                l[ki] = l[ki] * sc + w;
#pragma unroll
                for (int d = 0; d < 16; ++d)
                    ca[ki][d] = fmaf(ca[ki][d], sc, w * kv[d]);
            }
        }

#pragma unroll
        for (int ki = 0; ki < 2; ++ki) {
            int kg = kt * 32 + ki * 16 + kl;
            float inv = (dg && kg > qg) ? 0.f : (1.f / l[ki]);
#pragma unroll
            for (int d = 0; d < 16; ++d) ctx[d] = fmaf(ca[ki][d], inv, ctx[d]);
        }
    }

    int pqt = curX ? qtB : qtA;
#pragma unroll
    for (int d = 0; d < 16; ++d) {
        float v = ctx[d];
        v += __shfl_xor(v, 1);
        v += __shfl_xor(v, 2);
        v += __shfl_xor(v, 4);
        v += __shfl_xor(v, 8);
        if (kl == 0)
            atomicAdd(&out[(((size_t)b * 8 + h) * 512 + pqt * 32 + q) * 16 + d], v);
    }
}

// ---------------------------------------------------------------------------
extern "C" void kernel_launch(void* const* d_in, const int* in_sizes, int n_in,
                              void* d_out, int out_size, void* d_ws, size_t ws_size,
                              hipStream_t stream) {
    const float* Q = (const float*)d_in[0];
    const float* K = (const float*)d_in[1];
    const float* W = (const float*)d_in[3];
    const float* bconv = (const float*)d_in[4];
    float* out = (float*)d_out;

    float* Y = (float*)d_ws;
    unsigned short* xr = (unsigned short*)((char*)d_ws + XR_OFF);
    unsigned short* wb = (unsigned short*)((char*)d_ws + WB_OFF);

    prep<<<2048, 256, 0, stream>>>(Q, K, xr, (float4*)Y, (float4*)out);

    repack_w<<<73 * 128, 256, 0, stream>>>(W, wb);

    conv_mfma<<<256, 256, 0, stream>>>(xr, wb, Y);

    suffix_ctx<<<16, 512, 0, stream>>>(Y, bconv, out);

    attn_phase2<<<256, 512, 0, stream>>>(Y, bconv, out);
}

// Round 11
// 250.107 us; speedup vs baseline: 1.0647x; 1.0647x over previous
//
#include <hip/hip_runtime.h>

// Problem constants
#define Bv 2
#define Hv 8
#define Lv 512
#define DKv 16
#define DMv 128          // H*DK
#define NKv 10
#define KSv 513

typedef __attribute__((ext_vector_type(8))) short short8;
typedef __attribute__((ext_vector_type(4))) float f32x4;

// chunk tables: nc_g = ceil((2^g+1)/16); chunks aligned to the END of the kernel
__device__ __constant__ int d_nc[10]     = {1,1,1,1,2,3,5,9,17,33};
__device__ __constant__ int d_cumnc[10]  = {0,1,2,3,4,6,9,14,23,40};
// total chunks = 73

// ws layout (bytes):
//   Y  : f32 [2 p][10 g][2 b][128 o][512 t]            = 10,485,760 B
//   xr : bf16 [2 p][2 b][512 t][128 i]                 =    524,288 B
//   Wb : bf16 [g][Tlocal][ A-frag layout ]             = 38,273,024 B
//        plane off(o,i) = ((o>>4)*4 + (i>>5))*512 + (o&15)*32 + (i&31)
#define Y_BYTES   (10485760)
#define XR_OFF    (Y_BYTES)
#define WB_OFF    (Y_BYTES + 524288)

__device__ inline unsigned short f2bf(float f) {
    unsigned u = __float_as_uint(f);
    unsigned r = (u + 0x7FFFu + ((u >> 16) & 1u)) >> 16;
    return (unsigned short)r;
}

// ---------------------------------------------------------------------------
// prep: fused  (a) zero Y planes g4..g9 (both p)  (b) attn_out := 1.0
//              (c) repack_x  xr[p][b][t][i] = bf16(flat Q/K)
__global__ void prep(const float* __restrict__ Q, const float* __restrict__ K,
                     unsigned short* __restrict__ xr,
                     float4* __restrict__ Y4, float4* __restrict__ out4) {
    int stride = gridDim.x * 256;
    for (int i = blockIdx.x * 256 + threadIdx.x; i < 1507328; i += stride) {
        if (i < 196608) {
            Y4[131072 + i] = make_float4(0.f, 0.f, 0.f, 0.f);            // p0 g4..9
        } else if (i < 393216) {
            Y4[458752 + (i - 196608)] = make_float4(0.f, 0.f, 0.f, 0.f); // p1 g4..9
        } else if (i < 1441792) {
            out4[32768 + (i - 393216)] = make_float4(1.f, 1.f, 1.f, 1.f);
        } else {
            int idx = i - 1441792;               // 65536 items of 4 floats
            int flat = idx * 4;
            int p = flat >> 17;
            int off = flat & 131071;
            const float* src = p ? K : Q;
            float4 v = *(const float4*)(src + off);
            ushort4 o;
            o.x = f2bf(v.x); o.y = f2bf(v.y); o.z = f2bf(v.z); o.w = f2bf(v.w);
            *(ushort4*)(((unsigned short*)xr) + flat) = o;
        }
    }
}

// ---------------------------------------------------------------------------
// Wb plane layout: off(o,i) = ((o>>4)*4 + (i>>5))*512 + (o&15)*32 + (i&31)
__global__ __launch_bounds__(256) void repack_w(const float* __restrict__ W,
                                                unsigned short* __restrict__ wb) {
    int bid = blockIdx.x;
    int cid = bid >> 7;
    int o = bid & 127;
    int g, rem = cid;
#pragma unroll
    for (g = 0; g < 10; ++g) { int nc = d_nc[g]; if (rem < nc) break; rem -= nc; }
    int cl = rem;
    int w_g = d_nc[g] * 16;
    int ccol = w_g - 16 * (cl + 1);
    int wcolbase = 513 - w_g + ccol;      // absolute W col of this chunk's tap 0

    __shared__ float tile[128][17];       // [i][tap]
    const float* wsrc = W + (size_t)g * 16384 * 513 + (size_t)o * 128 * 513;
    int tid = threadIdx.x;
    int rr = tid >> 4, cc = tid & 15;
    int col = wcolbase + cc;
    for (int r = rr; r < 128; r += 16) {          // r = i
        float v = 0.f;
        if (col >= 0) v = wsrc[(size_t)r * 513 + col];
        tile[r][cc] = v;
    }
    __syncthreads();

    unsigned short* wdst = wb + (size_t)262144 * d_cumnc[g];
    int c2 = tid >> 4;          // tap 0..15
    int s  = tid & 15;          // ib(2) | qv(2)
    int ib = s >> 2, qv = s & 3;
    int i0 = ib * 32 + qv * 8;
    unsigned short pack[8];
#pragma unroll
    for (int e = 0; e < 8; ++e) pack[e] = f2bf(tile[i0 + e][c2]);
    size_t off = (size_t)(ccol + c2) * 16384 +
                 (((o >> 4) * 4 + ib) * 512 + (o & 15) * 32 + qv * 8);
    *(short8*)(wdst + off) = *(short8*)pack;      // 16B contiguous per thread
}

// ---------------------------------------------------------------------------
// conv v7: uniform per-chunk blocks, tile M=128 x N=256, 4 waves (2wm x 2wn).
// A-frags streamed L2->regs (coalesced 1KB wave-loads), no inner barriers.
// cid<=3 (g0..g3, sole writer) -> plain store; else atomic.
// Grid 640: j -> r=j&7 (XCD), yy=(j>>3)&7, cid=(j>>6)*8+r.
__global__ __launch_bounds__(256, 2) void conv_mfma(const unsigned short* __restrict__ xr,
                                                    const unsigned short* __restrict__ wb,
                                                    float* __restrict__ Y) {
    int j = blockIdx.x;
    int r = j & 7, yy = (j >> 3) & 7, qq = j >> 6;
    int cid = qq * 8 + r;
    if (cid >= 73) return;
    int g, rem = cid;
#pragma unroll
    for (g = 0; g < 10; ++g) { int nc = d_nc[g]; if (rem < nc) break; rem -= nc; }
    int cl = rem;
    int w_g = d_nc[g] * 16;
    int ccol = w_g - 16 * (cl + 1);

    int p = yy >> 2, b = (yy >> 1) & 1, tt = yy & 1;
    int t0 = tt * 256;
    int pb = yy >> 1;

    int xbase = t0 + 1 - 16 * (cl + 1);    // x index of xs row 0
    if (xbase < -270) return;              // read window [0,270] entirely < 0

    // xs: element (u,i) at u*128 + (((i>>3)+u)&15)*8 + (i&7); 272 rows
    __shared__ unsigned short xs[272 * 128];

    int tid = threadIdx.x;
    const unsigned short* xp = xr + (size_t)pb * 65536;
    for (int e = tid; e < 272 * 16; e += 256) {
        int u = e >> 4, ic = e & 15;
        int xi = xbase + u;
        short8 v = (short8)0;
        if (xi >= 0 && xi < 512) v = *(const short8*)(xp + (size_t)xi * 128 + ic * 8);
        *(short8*)(&xs[u * 128 + (((ic + u) & 15) << 3)]) = v;
    }
    __syncthreads();                        // only barrier in the kernel

    int lane = tid & 63, wv = tid >> 6;     // 4 waves: 2 wm x 2 wn
    int wm = wv >> 1, wn = wv & 1;
    int l15 = lane & 15, q = lane >> 4;

    const unsigned short* wgp = wb + (size_t)262144 * d_cumnc[g] + (size_t)ccol * 16384;
    int abase = l15 * 32 + q * 8;

    f32x4 acc[4][8];
#pragma unroll
    for (int mt = 0; mt < 4; ++mt)
#pragma unroll
        for (int nt = 0; nt < 8; ++nt) acc[mt][nt] = (f32x4)0.f;

    for (int jj = 0; jj < 16; ++jj) {
        const unsigned short* tp = wgp + (size_t)jj * 16384;
        int row0 = wn * 128 + l15 + jj;
#pragma unroll
        for (int ib = 0; ib < 4; ++ib) {
            short8 a[4], bq[8];
#pragma unroll
            for (int mt = 0; mt < 4; ++mt)
                a[mt] = *(const short8*)(tp + ((wm * 4 + mt) * 4 + ib) * 512 + abase);
#pragma unroll
            for (int nt = 0; nt < 8; ++nt) {
                int row = row0 + nt * 16;
                bq[nt] = *(const short8*)(&xs[row * 128 + (((ib * 4 + q + row) & 15) << 3)]);
            }
#pragma unroll
            for (int mt = 0; mt < 4; ++mt)
#pragma unroll
                for (int nt = 0; nt < 8; ++nt)
                    acc[mt][nt] = __builtin_amdgcn_mfma_f32_16x16x32_bf16(
                        a[mt], bq[nt], acc[mt][nt], 0, 0, 0);
        }
    }

    // epilogue into Y[p][g][b][o][t]
    float* yp = Y + (((size_t)p * NKv + g) * 2 + b) * 65536;
    int orow = wm * 64 + q * 4;
    int tcol = t0 + wn * 128 + l15;
    if (cid <= 3) {
#pragma unroll
        for (int mt = 0; mt < 4; ++mt)
#pragma unroll
            for (int nt = 0; nt < 8; ++nt)
#pragma unroll
                for (int rr = 0; rr < 4; ++rr)
                    yp[(size_t)(orow + mt * 16 + rr) * 512 + tcol + nt * 16] =
                        acc[mt][nt][rr];
    } else {
#pragma unroll
        for (int mt = 0; mt < 4; ++mt)
#pragma unroll
            for (int nt = 0; nt < 8; ++nt)
#pragma unroll
                for (int rr = 0; rr < 4; ++rr)
                    atomicAdd(&yp[(size_t)(orow + mt * 16 + rr) * 512 + tcol + nt * 16],
                              acc[mt][nt][rr]);
    }
}

// ---------------------------------------------------------------------------
// Masked-entry context: ctx_masked[q,d] = 0.1 * sum_{k>q} S[k,d],
// S[k,d] = sum_g (K_p + bias). WRITES out ctx region.
__global__ __launch_bounds__(512) void suffix_ctx(const float* __restrict__ Y,
                                                  const float* __restrict__ bconv,
                                                  float* __restrict__ out) {
    int bh = blockIdx.x;        // 16
    int b = bh >> 3, h = bh & 7;
    int tid = threadIdx.x;
    int d = tid & 15;
    int s = tid >> 4;           // stripe 0..31, k in [s*16, s*16+16)

    __shared__ float tot[32][17];
    float S[16];
#pragma unroll
    for (int jv = 0; jv < 16; ++jv) {
        int k = s * 16 + jv;
        int o = h * 16 + (k >> 5);
        int t = (k & 31) * 16 + d;
        float acc = 0.f;
#pragma unroll
        for (int g = 0; g < NKv; ++g)
            acc += Y[(((size_t)(NKv + g) * 2 + b) * 65536) + (size_t)o * 512 + t]
                 + bconv[g * 128 + o];
        S[jv] = acc;
    }
    float mytot = 0.f;
#pragma unroll
    for (int jv = 0; jv < 16; ++jv) mytot += S[jv];
    tot[s][d] = mytot;
    __syncthreads();
    float run = 0.f;
    for (int s2 = s + 1; s2 < 32; ++s2) run += tot[s2][d];
#pragma unroll
    for (int jv = 15; jv >= 0; --jv) {
        int qv = s * 16 + jv;
        out[(((size_t)b * 8 + h) * 512 + qv) * 16 + d] = 0.1f * run;
        run += S[jv];
    }
}

// ---------------------------------------------------------------------------
// phase 2 (r9-verified f32 version): unmasked (k<=q) part, online softmax
// over g, 512 threads (32 q x 16 kl, 2 ki) -> 2 waves/SIMD.
__global__ __launch_bounds__(512) void attn_phase2(const float* __restrict__ Y,
                                                   const float* __restrict__ bconv,
                                                   float* __restrict__ out) {
    int blk = blockIdx.x;          // 256
    int half = blk & 1;
    int pr = blk >> 1;             // 128 pairs
    int bh = pr >> 3;
    int qp = pr & 7;
    int b = bh >> 3, h = bh & 7;

    int qtA = qp, qtB = 15 - qp;
    int u0 = half ? 8 : 0, u1 = half ? 17 : 8;

    __shared__ float Qs[2][NKv * 640];   // [X][g*640 + q*20 + d]
    __shared__ float Ks[NKv * 640];

    int tid = threadIdx.x;

#pragma unroll
    for (int X = 0; X < 2; ++X) {
        int o = h * 16 + (X ? qtB : qtA);
        for (int e = tid; e < NKv * 128; e += 512) {
            int g = e >> 7, c = e & 127;
            float4 v = *(const float4*)(Y + (((size_t)g * 2 + b) * 65536) +
                                        (size_t)o * 512 + c * 4);
            float bb = bconv[g * 128 + o];
            int qq2 = c >> 2, dd = c & 3;
            *(float4*)&Qs[X][g * 640 + qq2 * 20 + dd * 4] =
                make_float4(v.x + bb, v.y + bb, v.z + bb, v.w + bb);
        }
    }

    int q = (tid >> 4) & 31;
    int kl = tid & 15;
    float ctx[16];
#pragma unroll
    for (int d = 0; d < 16; ++d) ctx[d] = 0.f;
    int curX = (u0 <= qtA) ? 0 : 1;

    for (int u = u0; u < u1; ++u) {
        int X = (u <= qtA) ? 0 : 1;
        int qt = X ? qtB : qtA;
        int kt = X ? (u - qtA - 1) : u;

        if (X != curX) {
            int pqt = curX ? qtB : qtA;
#pragma unroll
            for (int d = 0; d < 16; ++d) {
                float v = ctx[d];
                v += __shfl_xor(v, 1);
                v += __shfl_xor(v, 2);
                v += __shfl_xor(v, 4);
                v += __shfl_xor(v, 8);
                if (kl == 0)
                    atomicAdd(&out[(((size_t)b * 8 + h) * 512 + pqt * 32 + q) * 16 + d], v);
                ctx[d] = 0.f;
            }
            curX = X;
        }

        __syncthreads();
        int o_k = h * 16 + kt;
        for (int e = tid; e < NKv * 128; e += 512) {
            int g = e >> 7, c = e & 127;
            float4 v = *(const float4*)(Y + (((size_t)(NKv + g) * 2 + b) * 65536) +
                                        (size_t)o_k * 512 + c * 4);
            float bb = bconv[g * 128 + o_k];
            int kk = c >> 2, dd = c & 3;
            *(float4*)&Ks[g * 640 + kk * 20 + dd * 4] =
                make_float4(v.x + bb, v.y + bb, v.z + bb, v.w + bb);
        }
        __syncthreads();

        int qg = qt * 32 + q;
        bool dg = (kt == qt);

        float m[2] = {-1e30f, -1e30f};
        float l[2] = {0.f, 0.f};
        float ca[2][16];
#pragma unroll
        for (int ki = 0; ki < 2; ++ki)
#pragma unroll
            for (int d = 0; d < 16; ++d) ca[ki][d] = 0.f;

        for (int g = 0; g < NKv; ++g) {
            const float* Qg = &Qs[X][g * 640 + q * 20];
            float4 qv0 = *(const float4*)(Qg);
            float4 qv1 = *(const float4*)(Qg + 4);
            float4 qv2 = *(const float4*)(Qg + 8);
            float4 qv3 = *(const float4*)(Qg + 12);
#pragma unroll
            for (int ki = 0; ki < 2; ++ki) {
                const float* Kg = &Ks[g * 640 + (ki * 16 + kl) * 20];
                float kv[16];
                *(float4*)&kv[0]  = *(const float4*)(Kg);
                *(float4*)&kv[4]  = *(const float4*)(Kg + 4);
                *(float4*)&kv[8]  = *(const float4*)(Kg + 8);
                *(float4*)&kv[12] = *(const float4*)(Kg + 12);
                float s = 0.f;
                s = fmaf(qv0.x, kv[0], s);  s = fmaf(qv0.y, kv[1], s);
                s = fmaf(qv0.z, kv[2], s);  s = fmaf(qv0.w, kv[3], s);
                s = fmaf(qv1.x, kv[4], s);  s = fmaf(qv1.y, kv[5], s);
                s = fmaf(qv1.z, kv[6], s);  s = fmaf(qv1.w, kv[7], s);
                s = fmaf(qv2.x, kv[8], s);  s = fmaf(qv2.y, kv[9], s);
                s = fmaf(qv2.z, kv[10], s); s = fmaf(qv2.w, kv[11], s);
                s = fmaf(qv3.x, kv[12], s); s = fmaf(qv3.y, kv[13], s);
                s = fmaf(qv3.z, kv[14], s); s = fmaf(qv3.w, kv[15], s);
                s *= 0.25f;
                float mn = fmaxf(m[ki], s);
                float sc = __expf(m[ki] - mn);
                float w  = __expf(s - mn);
                m[ki] = mn;
                l[ki] = l[ki] * sc + w;
#pragma unroll
                for (int d = 0; d < 16; ++d)
                    ca[ki][d] = fmaf(ca[ki][d], sc, w * kv[d]);
            }
        }

#pragma unroll
        for (int ki = 0; ki < 2; ++ki) {
            int kg = kt * 32 + ki * 16 + kl;
            float inv = (dg && kg > qg) ? 0.f : (1.f / l[ki]);
#pragma unroll
            for (int d = 0; d < 16; ++d) ctx[d] = fmaf(ca[ki][d], inv, ctx[d]);
        }
    }

    int pqt = curX ? qtB : qtA;
#pragma unroll
    for (int d = 0; d < 16; ++d) {
        float v = ctx[d];
        v += __shfl_xor(v, 1);
        v += __shfl_xor(v, 2);
        v += __shfl_xor(v, 4);
        v += __shfl_xor(v, 8);
        if (kl == 0)
            atomicAdd(&out[(((size_t)b * 8 + h) * 512 + pqt * 32 + q) * 16 + d], v);
    }
}

// ---------------------------------------------------------------------------
extern "C" void kernel_launch(void* const* d_in, const int* in_sizes, int n_in,
                              void* d_out, int out_size, void* d_ws, size_t ws_size,
                              hipStream_t stream) {
    const float* Q = (const float*)d_in[0];
    const float* K = (const float*)d_in[1];
    const float* W = (const float*)d_in[3];
    const float* bconv = (const float*)d_in[4];
    float* out = (float*)d_out;

    float* Y = (float*)d_ws;
    unsigned short* xr = (unsigned short*)((char*)d_ws + XR_OFF);
    unsigned short* wb = (unsigned short*)((char*)d_ws + WB_OFF);

    prep<<<2048, 256, 0, stream>>>(Q, K, xr, (float4*)Y, (float4*)out);

    repack_w<<<73 * 128, 256, 0, stream>>>(W, wb);

    conv_mfma<<<640, 256, 0, stream>>>(xr, wb, Y);

    suffix_ctx<<<16, 512, 0, stream>>>(Y, bconv, out);

    attn_phase2<<<256, 512, 0, stream>>>(Y, bconv, out);
}